// Round 6
// baseline (402.036 us; speedup 1.0000x reference)
//
#include <hip/hip_runtime.h>
#include <hip/hip_cooperative_groups.h>
#include <hip/hip_bf16.h>
#include <math.h>

namespace cg = cooperative_groups;

typedef float v4f __attribute__((ext_vector_type(4)));
typedef __bf16 bf16x8 __attribute__((ext_vector_type(8)));
typedef __bf16 bf16x4 __attribute__((ext_vector_type(4)));

#define NN   1024
#define INF  128
#define H0C  192
#define H1C  96

// ws byte offsets
#define WS_W0BF   0        // 24576 bf16 (A-frag order, BN0 scale folded)
#define WS_W1BF   49152    // 18432 bf16 (A-frag order, BN1 scale folded)
#define WS_BN0SW  86016    // 192 f32: [q][cm][r] = bias0[16cm+4q+r]
#define WS_BN1SW  86784    // 96 f32:  [q][mt][r] = bias1[16mt+4q+r]
#define WS_WOUTSW 87168    // 96 f32:  [q][mt][r] = wout[16mt+4q+r]
#define WS_CINV   87552    // 1024 f32 (written phase 2, read phase 3)
#define WS_CTR    87552    // work-steal counter; aliases cinv[0] -- counter is
                           // live only in phase 1, cinv[0] written in phase 2.

// ---------------------------------------------------------------------------
// R18: ONE cooperative kernel. R17 experiment refuted the occupancy theory
// (Occ 27->57% yet main 72.5->136us): per-block fixed costs dominate, R13's
// full-tile structure is the local optimum. The remaining pool is the ~74us
// of NON-main time (R13), mostly per-launch overhead (~11us/launch measured
// via R13->R14 delta). Fuse all 4 kernels with grid.sync() between phases:
//   phase 0: prep (174 virtual blocks, stride loop; counter init)
//   phase 1: R13 main body BIT-EXACT, tiles via atomic work-steal counter
//   phase 2: cinv rows (R0 cinv_kernel math, wave per row)
//   phase 3: edge rows (R0 edge_kernel body, block-stride)
// Grid = occupancy*256 (expected 3*256=768; LDS 51220*3 <= 160K, VGPR 84).
// ---------------------------------------------------------------------------
__global__ __launch_bounds__(256, 3) void edgenet_fused(
    const float* __restrict__ feat,
    const float* __restrict__ W0, const float* __restrict__ g0,
    const float* __restrict__ b0, const float* __restrict__ m0,
    const float* __restrict__ v0, const float* __restrict__ W1,
    const float* __restrict__ g1, const float* __restrict__ b1,
    const float* __restrict__ m1, const float* __restrict__ v1,
    const float* __restrict__ Wout, const float* __restrict__ boutp,
    char* __restrict__ ws, float* __restrict__ sim_out,
    float* __restrict__ edge)
{
    __shared__ __align__(16) char smem[51200];   // X then H0 (overlay)
    __shared__ int tsh;
    const int tid = threadIdx.x;
    const int lane = tid & 63;
    const int wave = tid >> 6;
    const int l16 = lane & 15;
    const int quad = lane >> 4;
    const int nb = gridDim.x;

    // ================= phase 0: prep [validated round 7] =================
    {
        __bf16* w0bf = (__bf16*)(ws + WS_W0BF);
        __bf16* w1bf = (__bf16*)(ws + WS_W1BF);
        float* bn0sw = (float*)(ws + WS_BN0SW);
        float* bn1sw = (float*)(ws + WS_BN1SW);
        float* woutsw = (float*)(ws + WS_WOUTSW);
        for (int vb = blockIdx.x; vb < 174; vb += nb) {
            int e = vb * 256 + tid;
            if (e < 24576) {                       // W0: 12 mtiles x 4 ksteps
                int j = e & 7, ln = (e >> 3) & 63, t = e >> 9;
                int ks = t & 3, mt = t >> 2;
                int c = mt * 16 + (ln & 15);
                int k = ks * 32 + ((ln >> 4) << 3) + j;
                float s = g0[c] * rsqrtf(v0[c] + 1e-5f);
                w0bf[e] = (__bf16)(W0[c * INF + k] * s);
            } else if (e < 43008) {                // W1: 6 mtiles x 6 ksteps
                int e2 = e - 24576;
                int j = e2 & 7, ln = (e2 >> 3) & 63, t = e2 >> 9;
                int ks = t % 6, mt = t / 6;
                int c = mt * 16 + (ln & 15);
                int k = ks * 32 + ((ln >> 4) << 3) + j;
                float s = g1[c] * rsqrtf(v1[c] + 1e-5f);
                w1bf[e2] = (__bf16)(W1[c * H0C + k] * s);
            } else if (e < 43200) {                // bn0 bias swizzled
                int e3 = e - 43008;
                int q = e3 / 48, rem = e3 % 48, cm = rem >> 2, r = rem & 3;
                int c = cm * 16 + q * 4 + r;
                float s = g0[c] * rsqrtf(v0[c] + 1e-5f);
                bn0sw[e3] = b0[c] - m0[c] * s;
            } else if (e < 43296) {                // bn1 bias swizzled
                int e4 = e - 43200;
                int q = e4 / 24, rem = e4 % 24, mt = rem >> 2, r = rem & 3;
                int c = mt * 16 + q * 4 + r;
                float s = g1[c] * rsqrtf(v1[c] + 1e-5f);
                bn1sw[e4] = b1[c] - m1[c] * s;
            } else if (e < 43392) {                // wout swizzled
                int e5 = e - 43296;
                int q = e5 / 24, rem = e5 % 24, mt = rem >> 2, r = rem & 3;
                woutsw[e5] = Wout[mt * 16 + q * 4 + r];
            } else if (e == 43392) {               // work-steal counter init
                atomicExch((int*)(ws + WS_CTR), 0);
            }
        }
    }
    cg::this_grid().sync();

    // ================= phase 1: main tiles (R13 body, work-stealing) =====
    {
        const bf16x8* w0v = (const bf16x8*)(ws + WS_W0BF);
        const bf16x8* w1v = (const bf16x8*)(ws + WS_W1BF);
        const float* bn0sw = (const float*)(ws + WS_BN0SW);
        const float* bn1sw = (const float*)(ws + WS_BN1SW);
        const float* woutsw = (const float*)(ws + WS_WOUTSW);
        for (;;) {
            if (tid == 0) tsh = atomicAdd((int*)(ws + WS_CTR), 1);
            __syncthreads();   // broadcast id; also protects LDS reuse
            const int id = tsh;
            if (id >= 4160) break;

            // triangular tile id -> (bi, bj): cum(bi) = bi*(129-bi)
            int bi = (int)((129.0f - sqrtf(16641.0f - 4.0f * (float)id)) * 0.5f);
            while (bi > 0 && bi * (129 - bi) > id) --bi;
            while ((bi + 1) * (128 - bi) <= id) ++bi;
            const int bj = 2 * bi + (id - bi * (129 - bi));
            const int i0 = bi << 4;
            const int j0 = bj << 3;
            const int jb = j0 + wave * 2;

            // ---- X gen: fi once, stream 8 fj rows [R8-verified] ----
            {
                int ii = tid & 15, fblk = tid >> 4;
                const float* fi = feat + (i0 + ii) * INF + fblk * 8;
                float4 a0 = *(const float4*)fi;
                float4 a1 = *(const float4*)(fi + 4);
                const float* fj = feat + j0 * INF + fblk * 8;
                char* sp = smem + ii * 272 + fblk * 16;
                #pragma unroll
                for (int jj = 0; jj < 8; ++jj) {
                    float4 q0 = *(const float4*)fj;
                    float4 q1 = *(const float4*)(fj + 4);
                    bf16x8 x;
                    x[0] = (__bf16)fabsf(a0.x - q0.x);
                    x[1] = (__bf16)fabsf(a0.y - q0.y);
                    x[2] = (__bf16)fabsf(a0.z - q0.z);
                    x[3] = (__bf16)fabsf(a0.w - q0.w);
                    x[4] = (__bf16)fabsf(a1.x - q1.x);
                    x[5] = (__bf16)fabsf(a1.y - q1.y);
                    x[6] = (__bf16)fabsf(a1.z - q1.z);
                    x[7] = (__bf16)fabsf(a1.w - q1.w);
                    *(bf16x8*)sp = x;
                    fj += INF;
                    sp += 16 * 272;
                }
            }
            __syncthreads();

            // ---- Layer 1: two nt-halves; results packed to bf16 regs ----
            bf16x4 pk[2][3][4];
            #pragma unroll
            for (int h = 0; h < 2; ++h) {
                v4f acch[3][4];
                #pragma unroll
                for (int mt = 0; mt < 3; ++mt) {
                    v4f bb = *(const v4f*)(bn0sw + (quad * 12 + wave * 3 + mt) * 4);
                    #pragma unroll
                    for (int nt = 0; nt < 4; ++nt)
                        acch[mt][nt] = bb;
                }
                #pragma unroll
                for (int ks = 0; ks < 4; ++ks) {
                    bf16x8 w0a = w0v[((wave * 3 + 0) * 4 + ks) * 64 + lane];
                    bf16x8 w0b = w0v[((wave * 3 + 1) * 4 + ks) * 64 + lane];
                    bf16x8 w0c = w0v[((wave * 3 + 2) * 4 + ks) * 64 + lane];
                    #pragma unroll
                    for (int nt = 0; nt < 4; ++nt) {
                        bf16x8 xk = *(const bf16x8*)(smem +
                            ((h * 4 + nt) * 16 + l16) * 272 + ks * 64 + quad * 16);
                        acch[0][nt] = __builtin_amdgcn_mfma_f32_16x16x32_bf16(
                            w0a, xk, acch[0][nt], 0, 0, 0);
                        acch[1][nt] = __builtin_amdgcn_mfma_f32_16x16x32_bf16(
                            w0b, xk, acch[1][nt], 0, 0, 0);
                        acch[2][nt] = __builtin_amdgcn_mfma_f32_16x16x32_bf16(
                            w0c, xk, acch[2][nt], 0, 0, 0);
                    }
                }
                // leaky + pack -> bf16 VGPRs
                #pragma unroll
                for (int mt = 0; mt < 3; ++mt)
                    #pragma unroll
                    for (int nt = 0; nt < 4; ++nt) {
                        bf16x4 p;
                        #pragma unroll
                        for (int r = 0; r < 4; ++r) {
                            float v = acch[mt][nt][r];
                            v = fmaxf(v, 0.01f * v);
                            p[r] = (__bf16)v;
                        }
                        pk[h][mt][nt] = p;
                    }
            }
            __syncthreads();   // all X reads done; H0 may overlay

            // ---- H0 write: 24 ds_write_b64 from the packed regs ----
            #pragma unroll
            for (int h = 0; h < 2; ++h)
                #pragma unroll
                for (int mt = 0; mt < 3; ++mt) {
                    int chb = (wave * 3 + mt) * 16 + quad * 4;
                    #pragma unroll
                    for (int nt = 0; nt < 4; ++nt)
                        *(bf16x4*)(smem + ((h * 4 + nt) * 16 + l16) * 400 + chb * 2)
                            = pk[h][mt][nt];
                }
            __syncthreads();   // H0 complete (cross-wave channels)

            // ---- Layer 2: wave owns pair ntiles {2w, 2w+1}; full W1 ----
            v4f acc2[6][2];
            #pragma unroll
            for (int mt = 0; mt < 6; ++mt) {
                v4f bb = *(const v4f*)(bn1sw + (quad * 6 + mt) * 4);
                acc2[mt][0] = bb;
                acc2[mt][1] = bb;
            }
            #pragma unroll
            for (int ks = 0; ks < 6; ++ks) {
                bf16x8 h0 = *(const bf16x8*)(smem + ((2 * wave + 0) * 16 + l16) * 400 + ks * 64 + quad * 16);
                bf16x8 h1 = *(const bf16x8*)(smem + ((2 * wave + 1) * 16 + l16) * 400 + ks * 64 + quad * 16);
                #pragma unroll
                for (int mt = 0; mt < 6; ++mt) {
                    bf16x8 w = w1v[(mt * 6 + ks) * 64 + lane];
                    acc2[mt][0] = __builtin_amdgcn_mfma_f32_16x16x32_bf16(w, h0, acc2[mt][0], 0, 0, 0);
                    acc2[mt][1] = __builtin_amdgcn_mfma_f32_16x16x32_bf16(w, h1, acc2[mt][1], 0, 0, 0);
                }
            }

            // ---- epilogue: leaky + dot(wout) + cross-quad butterfly ----
            float part[2] = {0.f, 0.f};
            #pragma unroll
            for (int mt = 0; mt < 6; ++mt) {
                v4f wo = *(const v4f*)(woutsw + (quad * 6 + mt) * 4);
                #pragma unroll
                for (int t = 0; t < 2; ++t)
                    #pragma unroll
                    for (int r = 0; r < 4; ++r) {
                        float v = acc2[mt][t][r];
                        v = fmaxf(v, 0.01f * v);
                        part[t] = fmaf(v, wo[r], part[t]);
                    }
            }
            #pragma unroll
            for (int t = 0; t < 2; ++t) {
                part[t] += __shfl_xor(part[t], 16, 64);
                part[t] += __shfl_xor(part[t], 32, 64);
            }
            float z = (quad & 1) ? part[1] : part[0];
            float sv = 1.f / (1.f + expf(-(z + boutp[0])));
            if (quad < 2)
                sim_out[(i0 + l16) * NN + jb + (quad & 1)] = sv;    // direct
            else
                sim_out[(jb + (quad & 1)) * NN + i0 + l16] = sv;    // mirror
        }
    }
    cg::this_grid().sync();

    // ================= phase 2: cinv rows (exact symmetry) ===============
    {
        float* cinvp = (float*)(ws + WS_CINV);
        const float cadd = 1.0f + (float)NN * 1e-6f;
        for (int j = blockIdx.x * 4 + wave; j < NN; j += nb * 4) {
            const float4* row = (const float4*)(sim_out + j * NN);
            float4 a0 = row[lane];
            float4 a1 = row[lane + 64];
            float4 a2 = row[lane + 128];
            float4 a3 = row[lane + 192];
            float s = (a0.x + a0.y + a0.z + a0.w) + (a1.x + a1.y + a1.z + a1.w)
                    + (a2.x + a2.y + a2.z + a2.w) + (a3.x + a3.y + a3.z + a3.w);
            #pragma unroll
            for (int off = 1; off < 64; off <<= 1)
                s += __shfl_xor(s, off, 64);
            if (lane == 0)
                cinvp[j] = 1.0f / (s + cadd);
        }
    }
    cg::this_grid().sync();

    // ================= phase 3: edge rows ================================
    {
        const float* cinvp = (const float*)(ws + WS_CINV);
        for (int i = blockIdx.x; i < NN; i += nb) {
            int jc = tid << 2;
            float4 w = *(const float4*)(cinvp + jc);
            float4 s = *(const float4*)(sim_out + i * NN + jc);
            float4 o;
            o.x = (s.x + (i == jc + 0 ? 1.f : 0.f) + 1e-6f) * w.x;
            o.y = (s.y + (i == jc + 1 ? 1.f : 0.f) + 1e-6f) * w.y;
            o.z = (s.z + (i == jc + 2 ? 1.f : 0.f) + 1e-6f) * w.z;
            o.w = (s.w + (i == jc + 3 ? 1.f : 0.f) + 1e-6f) * w.w;
            *(float4*)(edge + i * NN + jc) = o;
        }
    }
}

extern "C" void kernel_launch(void* const* d_in, const int* in_sizes, int n_in,
                              void* d_out, int out_size, void* d_ws, size_t ws_size,
                              hipStream_t stream)
{
    const float* feat = (const float*)d_in[0];
    const float* W0   = (const float*)d_in[1];
    const float* g0   = (const float*)d_in[2];
    const float* b0   = (const float*)d_in[3];
    const float* m0   = (const float*)d_in[4];
    const float* v0   = (const float*)d_in[5];
    const float* W1   = (const float*)d_in[6];
    const float* g1   = (const float*)d_in[7];
    const float* b1   = (const float*)d_in[8];
    const float* m1   = (const float*)d_in[9];
    const float* v1   = (const float*)d_in[10];
    const float* Wout = (const float*)d_in[11];
    const float* bout = (const float*)d_in[12];
    char* ws = (char*)d_ws;
    float* edge = (float*)d_out;
    float* sim  = edge + NN * NN;

    // grid = co-resident capacity (LDS-capped at 3 blocks/CU -> 768 expected)
    static int s_grid = 0;
    if (s_grid == 0) {
        int occ = 0;
        if (hipOccupancyMaxActiveBlocksPerMultiprocessor(
                &occ, (const void*)edgenet_fused, 256, 0) != hipSuccess || occ <= 0)
            occ = 3;
        if (occ > 3) occ = 3;
        s_grid = occ * 256;
    }

    void* kargs[] = {
        (void*)&feat, (void*)&W0, (void*)&g0, (void*)&b0, (void*)&m0,
        (void*)&v0, (void*)&W1, (void*)&g1, (void*)&b1, (void*)&m1,
        (void*)&v1, (void*)&Wout, (void*)&bout, (void*)&ws, (void*)&sim,
        (void*)&edge
    };
    hipLaunchCooperativeKernel((const void*)edgenet_fused, dim3(s_grid),
                               dim3(256), kargs, 0, stream);
}

// Round 7
// 160.202 us; speedup vs baseline: 2.5096x; 2.5096x over previous
//
#include <hip/hip_runtime.h>
#include <hip/hip_bf16.h>
#include <math.h>

typedef float v4f __attribute__((ext_vector_type(4)));
typedef __bf16 bf16x8 __attribute__((ext_vector_type(8)));
typedef __bf16 bf16x4 __attribute__((ext_vector_type(4)));

#define NN   1024
#define INF  128
#define H0C  192
#define H1C  96

// ws byte offsets
#define WS_W0BF   0        // 24576 bf16 (A-frag order, BN0 scale folded)
#define WS_W1BF   49152    // 18432 bf16 (A-frag order, BN1 scale folded)
#define WS_BN0SW  86016    // 192 f32: [q][cm][r] = bias0[16cm+4q+r]
#define WS_BN1SW  86784    // 96 f32:  [q][mt][r] = bias1[16mt+4q+r]
#define WS_WOUTSW 87168    // 96 f32:  [q][mt][r] = wout[16mt+4q+r]
#define WS_CSUM   87552    // 1024 f32 column sums (atomic-accumulated)

// ---------------------------------------------------------------------------
// Prep. A-frag (16x16x32): lane holds A[m=l16][k=quad*8+j];
// flat [(mtile*KS+ks)*64 + lane]*8 + j, m = channel, k = input dim.
// Biases and wout pre-swizzled to C-layout register order [q][mt][r].
// Also zeroes the colsum accumulator for this iteration. [validated R14]
// ---------------------------------------------------------------------------
__global__ __launch_bounds__(256) void prep_kernel(
    const float* __restrict__ W0, const float* __restrict__ g0,
    const float* __restrict__ b0, const float* __restrict__ m0,
    const float* __restrict__ v0, const float* __restrict__ W1,
    const float* __restrict__ g1, const float* __restrict__ b1,
    const float* __restrict__ m1, const float* __restrict__ v1,
    const float* __restrict__ Wout, char* __restrict__ ws)
{
    int e = blockIdx.x * 256 + threadIdx.x;
    __bf16* w0bf = (__bf16*)(ws + WS_W0BF);
    __bf16* w1bf = (__bf16*)(ws + WS_W1BF);
    float* bn0sw = (float*)(ws + WS_BN0SW);
    float* bn1sw = (float*)(ws + WS_BN1SW);
    float* woutsw = (float*)(ws + WS_WOUTSW);
    float* csum = (float*)(ws + WS_CSUM);
    if (e < 24576) {                       // W0: 12 mtiles x 4 ksteps
        int j = e & 7, lane = (e >> 3) & 63, t = e >> 9;
        int ks = t & 3, mt = t >> 2;
        int c = mt * 16 + (lane & 15);               // m = H0 channel
        int k = ks * 32 + ((lane >> 4) << 3) + j;    // k = input feature
        float s = g0[c] * rsqrtf(v0[c] + 1e-5f);
        w0bf[e] = (__bf16)(W0[c * INF + k] * s);
    } else if (e < 43008) {                // W1: 6 mtiles x 6 ksteps
        int e2 = e - 24576;
        int j = e2 & 7, lane = (e2 >> 3) & 63, t = e2 >> 9;
        int ks = t % 6, mt = t / 6;
        int c = mt * 16 + (lane & 15);               // m = H1 channel
        int k = ks * 32 + ((lane >> 4) << 3) + j;    // k = H0 channel
        float s = g1[c] * rsqrtf(v1[c] + 1e-5f);
        w1bf[e2] = (__bf16)(W1[c * H0C + k] * s);
    } else if (e < 43200) {                // bn0 bias swizzled [q][cm][r]
        int e3 = e - 43008;
        int q = e3 / 48, rem = e3 % 48, cm = rem >> 2, r = rem & 3;
        int c = cm * 16 + q * 4 + r;
        float s = g0[c] * rsqrtf(v0[c] + 1e-5f);
        bn0sw[e3] = b0[c] - m0[c] * s;
    } else if (e < 43296) {                // bn1 bias swizzled [q][mt][r]
        int e4 = e - 43200;
        int q = e4 / 24, rem = e4 % 24, mt = rem >> 2, r = rem & 3;
        int c = mt * 16 + q * 4 + r;
        float s = g1[c] * rsqrtf(v1[c] + 1e-5f);
        bn1sw[e4] = b1[c] - m1[c] * s;
    } else if (e < 43392) {                // wout swizzled [q][mt][r]
        int e5 = e - 43296;
        int q = e5 / 24, rem = e5 % 24, mt = rem >> 2, r = rem & 3;
        woutsw[e5] = Wout[mt * 16 + q * 4 + r];
    } else if (e < 44416) {                // zero colsum accumulator
        csum[e - 43392] = 0.f;
    }
}

// ---------------------------------------------------------------------------
// Main kernel, R19 = R13 BODY VERBATIM (the 72.5us / MfmaUtil 26 optimum;
// R14/R15/R16/R17/R18 restructures all regressed or failed) + fused csum
// tail using only R17-validated constructs (full-wave shfls, predicated
// atomics, tile-level exact-dedup predicate). cinv kernel deleted.
// Symmetry: triangular tiles bj >= 2*bi (4160 blocks); identical values at
// (i,j) and (j,i).
// ---------------------------------------------------------------------------
__global__ __launch_bounds__(256, 3) void edgenet_main(
    const float* __restrict__ feat, const char* __restrict__ ws,
    const float* __restrict__ boutp, float* __restrict__ sim_out,
    float* __restrict__ csum)
{
    __shared__ __align__(16) char smem[51200];   // X then H0 (overlay)
    const int tid = threadIdx.x;
    const int lane = tid & 63;
    const int wave = tid >> 6;
    const int l16 = lane & 15;
    const int quad = lane >> 4;

    // decode triangular tile id -> (bi, bj): cum(bi) = bi*(129-bi)  [R2-verified]
    const int id = blockIdx.x;
    int bi = (int)((129.0f - sqrtf(16641.0f - 4.0f * (float)id)) * 0.5f);
    while (bi > 0 && bi * (129 - bi) > id) --bi;
    while ((bi + 1) * (128 - bi) <= id) ++bi;
    const int bj = 2 * bi + (id - bi * (129 - bi));
    const int i0 = bi << 4;
    const int j0 = bj << 3;
    const int jb = j0 + wave * 2;

    // ---- X gen: fi once, stream 8 fj rows [R8-verified] ----
    {
        int ii = tid & 15, fblk = tid >> 4;
        const float* fi = feat + (i0 + ii) * INF + fblk * 8;
        float4 a0 = *(const float4*)fi;
        float4 a1 = *(const float4*)(fi + 4);
        const float* fj = feat + j0 * INF + fblk * 8;
        char* sp = smem + ii * 272 + fblk * 16;
        #pragma unroll
        for (int jj = 0; jj < 8; ++jj) {
            float4 q0 = *(const float4*)fj;
            float4 q1 = *(const float4*)(fj + 4);
            bf16x8 x;
            x[0] = (__bf16)fabsf(a0.x - q0.x);
            x[1] = (__bf16)fabsf(a0.y - q0.y);
            x[2] = (__bf16)fabsf(a0.z - q0.z);
            x[3] = (__bf16)fabsf(a0.w - q0.w);
            x[4] = (__bf16)fabsf(a1.x - q1.x);
            x[5] = (__bf16)fabsf(a1.y - q1.y);
            x[6] = (__bf16)fabsf(a1.z - q1.z);
            x[7] = (__bf16)fabsf(a1.w - q1.w);
            *(bf16x8*)sp = x;
            fj += INF;
            sp += 16 * 272;
        }
    }
    __syncthreads();

    const bf16x8* w0v = (const bf16x8*)(ws + WS_W0BF);
    const bf16x8* w1v = (const bf16x8*)(ws + WS_W1BF);
    const float* bn0sw = (const float*)(ws + WS_BN0SW);
    const float* bn1sw = (const float*)(ws + WS_BN1SW);

    // ---- Layer 1: two nt-halves; acc 48 AGPR; results packed to bf16 regs --
    bf16x4 pk[2][3][4];
    #pragma unroll
    for (int h = 0; h < 2; ++h) {
        v4f acch[3][4];
        #pragma unroll
        for (int mt = 0; mt < 3; ++mt) {
            v4f bb = *(const v4f*)(bn0sw + (quad * 12 + wave * 3 + mt) * 4);
            #pragma unroll
            for (int nt = 0; nt < 4; ++nt)
                acch[mt][nt] = bb;
        }
        #pragma unroll
        for (int ks = 0; ks < 4; ++ks) {
            bf16x8 w0a = w0v[((wave * 3 + 0) * 4 + ks) * 64 + lane];
            bf16x8 w0b = w0v[((wave * 3 + 1) * 4 + ks) * 64 + lane];
            bf16x8 w0c = w0v[((wave * 3 + 2) * 4 + ks) * 64 + lane];
            #pragma unroll
            for (int nt = 0; nt < 4; ++nt) {
                bf16x8 xk = *(const bf16x8*)(smem +
                    ((h * 4 + nt) * 16 + l16) * 272 + ks * 64 + quad * 16);
                acch[0][nt] = __builtin_amdgcn_mfma_f32_16x16x32_bf16(
                    w0a, xk, acch[0][nt], 0, 0, 0);
                acch[1][nt] = __builtin_amdgcn_mfma_f32_16x16x32_bf16(
                    w0b, xk, acch[1][nt], 0, 0, 0);
                acch[2][nt] = __builtin_amdgcn_mfma_f32_16x16x32_bf16(
                    w0c, xk, acch[2][nt], 0, 0, 0);
            }
        }
        // leaky + pack -> bf16 VGPRs (frees the 48 AGPRs for the next half)
        #pragma unroll
        for (int mt = 0; mt < 3; ++mt)
            #pragma unroll
            for (int nt = 0; nt < 4; ++nt) {
                bf16x4 p;
                #pragma unroll
                for (int r = 0; r < 4; ++r) {
                    float v = acch[mt][nt][r];
                    v = fmaxf(v, 0.01f * v);
                    p[r] = (__bf16)v;
                }
                pk[h][mt][nt] = p;
            }
    }
    __syncthreads();   // all X reads done; H0 may overlay

    // ---- H0 write: 24 ds_write_b64 from the packed regs ----
    #pragma unroll
    for (int h = 0; h < 2; ++h)
        #pragma unroll
        for (int mt = 0; mt < 3; ++mt) {
            int chb = (wave * 3 + mt) * 16 + quad * 4;
            #pragma unroll
            for (int nt = 0; nt < 4; ++nt)
                *(bf16x4*)(smem + ((h * 4 + nt) * 16 + l16) * 400 + chb * 2)
                    = pk[h][mt][nt];
        }
    __syncthreads();   // H0 complete (cross-wave channels)

    // ---- Layer 2: wave owns pair ntiles {2w, 2w+1}; H0 rows are B-frags ----
    v4f acc2[6][2];
    #pragma unroll
    for (int mt = 0; mt < 6; ++mt) {
        v4f bb = *(const v4f*)(bn1sw + (quad * 6 + mt) * 4);
        acc2[mt][0] = bb;
        acc2[mt][1] = bb;
    }
    #pragma unroll
    for (int ks = 0; ks < 6; ++ks) {
        bf16x8 h0 = *(const bf16x8*)(smem + ((2 * wave + 0) * 16 + l16) * 400 + ks * 64 + quad * 16);
        bf16x8 h1 = *(const bf16x8*)(smem + ((2 * wave + 1) * 16 + l16) * 400 + ks * 64 + quad * 16);
        #pragma unroll
        for (int mt = 0; mt < 6; ++mt) {
            bf16x8 w = w1v[(mt * 6 + ks) * 64 + lane];
            acc2[mt][0] = __builtin_amdgcn_mfma_f32_16x16x32_bf16(w, h0, acc2[mt][0], 0, 0, 0);
            acc2[mt][1] = __builtin_amdgcn_mfma_f32_16x16x32_bf16(w, h1, acc2[mt][1], 0, 0, 0);
        }
    }

    // ---- epilogue: leaky + dot(wout) + cross-quad butterfly + sigmoid ----
    const float* woutsw = (const float*)(ws + WS_WOUTSW);
    float part[2] = {0.f, 0.f};
    #pragma unroll
    for (int mt = 0; mt < 6; ++mt) {
        v4f wo = *(const v4f*)(woutsw + (quad * 6 + mt) * 4);
        #pragma unroll
        for (int t = 0; t < 2; ++t)
            #pragma unroll
            for (int r = 0; r < 4; ++r) {
                float v = acc2[mt][t][r];
                v = fmaxf(v, 0.01f * v);
                part[t] = fmaf(v, wo[r], part[t]);
            }
    }
    #pragma unroll
    for (int t = 0; t < 2; ++t) {
        part[t] += __shfl_xor(part[t], 16, 64);
        part[t] += __shfl_xor(part[t], 32, 64);
    }
    float z = (quad & 1) ? part[1] : part[0];
    float sv = 1.f / (1.f + expf(-(z + boutp[0])));
    if (quad < 2)
        sim_out[(i0 + l16) * NN + jb + (quad & 1)] = sv;        // direct
    else
        sim_out[(jb + (quad & 1)) * NN + i0 + l16] = sv;        // mirror, 64B runs

    // ---- fused csum (R17-validated constructs; exact-once coverage) ----
    // Lane (l16, quad) holds sv for cell (i0+l16, jb+(quad&1)); quads 2/3
    // duplicate quads 0/1 values.
    // Direct: colsum[jb+t] += sum_{l16} sv  (quad groups reduce via xor 1..8)
    float s = sv;
    s += __shfl_xor(s, 1, 64);
    s += __shfl_xor(s, 2, 64);
    s += __shfl_xor(s, 4, 64);
    s += __shfl_xor(s, 8, 64);
    if (l16 == 0 && quad < 2)
        atomicAdd(csum + jb + quad, s);            // 2 atomics/wave
    // Mirror: cell (a,b) = (jb+t, i0+l16) counts iff NOT direct-covered
    // globally: dup <=> (b>>3) >= 2*(a>>4)  [R14-verified predicate]
    bool dup = ((i0 + l16) >> 3) >= 2 * ((jb + (quad & 1)) >> 4);
    float ms = dup ? 0.f : sv;
    ms += __shfl_xor(ms, 16, 64);                  // quad2 += quad3
    if (quad == 2)
        atomicAdd(csum + i0 + l16, ms);            // 16 atomics/wave
}

// ---------------------------------------------------------------------------
// edge[i][j] = (sim + eye + 1e-6) / (colsum[j] + 1 + N*1e-6).  [R14-passed]
// ---------------------------------------------------------------------------
__global__ __launch_bounds__(256) void edge_kernel(
    const float* __restrict__ csum, const float* __restrict__ sim,
    float* __restrict__ edge)
{
    int i = blockIdx.x;
    int jc = threadIdx.x << 2;
    const float cadd = 1.0f + (float)NN * 1e-6f;
    float4 cs = *(const float4*)(csum + jc);
    float4 w;
    w.x = 1.0f / (cs.x + cadd);
    w.y = 1.0f / (cs.y + cadd);
    w.z = 1.0f / (cs.z + cadd);
    w.w = 1.0f / (cs.w + cadd);
    float4 s = *(const float4*)(sim + i * NN + jc);
    float4 o;
    o.x = (s.x + (i == jc + 0 ? 1.f : 0.f) + 1e-6f) * w.x;
    o.y = (s.y + (i == jc + 1 ? 1.f : 0.f) + 1e-6f) * w.y;
    o.z = (s.z + (i == jc + 2 ? 1.f : 0.f) + 1e-6f) * w.z;
    o.w = (s.w + (i == jc + 3 ? 1.f : 0.f) + 1e-6f) * w.w;
    *(float4*)(edge + i * NN + jc) = o;
}

extern "C" void kernel_launch(void* const* d_in, const int* in_sizes, int n_in,
                              void* d_out, int out_size, void* d_ws, size_t ws_size,
                              hipStream_t stream)
{
    const float* feat = (const float*)d_in[0];
    const float* W0   = (const float*)d_in[1];
    const float* g0   = (const float*)d_in[2];
    const float* b0   = (const float*)d_in[3];
    const float* m0   = (const float*)d_in[4];
    const float* v0   = (const float*)d_in[5];
    const float* W1   = (const float*)d_in[6];
    const float* g1   = (const float*)d_in[7];
    const float* b1   = (const float*)d_in[8];
    const float* m1   = (const float*)d_in[9];
    const float* v1   = (const float*)d_in[10];
    const float* Wout = (const float*)d_in[11];
    const float* bout = (const float*)d_in[12];
    char* ws = (char*)d_ws;
    float* edge = (float*)d_out;
    float* sim  = edge + NN * NN;
    float* csum = (float*)(ws + WS_CSUM);

    prep_kernel<<<dim3(174), dim3(256), 0, stream>>>(
        W0, g0, b0, m0, v0, W1, g1, b1, m1, v1, Wout, ws);
    edgenet_main<<<dim3(4160), dim3(256), 0, stream>>>(feat, ws, bout, sim, csum);
    edge_kernel<<<dim3(1024), dim3(256), 0, stream>>>(csum, sim, edge);
}

// Round 8
// 146.565 us; speedup vs baseline: 2.7430x; 1.0930x over previous
//
#include <hip/hip_runtime.h>
#include <hip/hip_bf16.h>
#include <math.h>

typedef float v4f __attribute__((ext_vector_type(4)));
typedef __bf16 bf16x8 __attribute__((ext_vector_type(8)));
typedef __bf16 bf16x4 __attribute__((ext_vector_type(4)));

#define NN   1024
#define INF  128
#define H0C  192
#define H1C  96

// ws byte offsets
#define WS_W0BF   0        // 24576 bf16 (A-frag order, BN0 scale folded)
#define WS_W1BF   49152    // 18432 bf16 (A-frag order, BN1 scale folded)
#define WS_BN0SW  86016    // 192 f32: [q][cm][r] = bias0[16cm+4q+r]
#define WS_BN1SW  86784    // 96 f32:  [q][mt][r] = bias1[16mt+4q+r]
#define WS_WOUTSW 87168    // 96 f32:  [q][mt][r] = wout[16mt+4q+r]
#define WS_CINV   87552    // 1024 f32

// ---------------------------------------------------------------------------
// Prep. A-frag (16x16x32): lane holds A[m=l16][k=quad*8+j];
// flat [(mtile*KS+ks)*64 + lane]*8 + j, m = channel, k = input dim.
// Biases and wout pre-swizzled to C-layout register order [q][mt][r].
// [validated round 7]
// ---------------------------------------------------------------------------
__global__ __launch_bounds__(256) void prep_kernel(
    const float* __restrict__ W0, const float* __restrict__ g0,
    const float* __restrict__ b0, const float* __restrict__ m0,
    const float* __restrict__ v0, const float* __restrict__ W1,
    const float* __restrict__ g1, const float* __restrict__ b1,
    const float* __restrict__ m1, const float* __restrict__ v1,
    const float* __restrict__ Wout, char* __restrict__ ws)
{
    int e = blockIdx.x * 256 + threadIdx.x;
    __bf16* w0bf = (__bf16*)(ws + WS_W0BF);
    __bf16* w1bf = (__bf16*)(ws + WS_W1BF);
    float* bn0sw = (float*)(ws + WS_BN0SW);
    float* bn1sw = (float*)(ws + WS_BN1SW);
    float* woutsw = (float*)(ws + WS_WOUTSW);
    if (e < 24576) {                       // W0: 12 mtiles x 4 ksteps
        int j = e & 7, lane = (e >> 3) & 63, t = e >> 9;
        int ks = t & 3, mt = t >> 2;
        int c = mt * 16 + (lane & 15);               // m = H0 channel
        int k = ks * 32 + ((lane >> 4) << 3) + j;    // k = input feature
        float s = g0[c] * rsqrtf(v0[c] + 1e-5f);
        w0bf[e] = (__bf16)(W0[c * INF + k] * s);
    } else if (e < 43008) {                // W1: 6 mtiles x 6 ksteps
        int e2 = e - 24576;
        int j = e2 & 7, lane = (e2 >> 3) & 63, t = e2 >> 9;
        int ks = t % 6, mt = t / 6;
        int c = mt * 16 + (lane & 15);               // m = H1 channel
        int k = ks * 32 + ((lane >> 4) << 3) + j;    // k = H0 channel
        float s = g1[c] * rsqrtf(v1[c] + 1e-5f);
        w1bf[e2] = (__bf16)(W1[c * H0C + k] * s);
    } else if (e < 43200) {                // bn0 bias swizzled [q][cm][r]
        int e3 = e - 43008;
        int q = e3 / 48, rem = e3 % 48, cm = rem >> 2, r = rem & 3;
        int c = cm * 16 + q * 4 + r;
        float s = g0[c] * rsqrtf(v0[c] + 1e-5f);
        bn0sw[e3] = b0[c] - m0[c] * s;
    } else if (e < 43296) {                // bn1 bias swizzled [q][mt][r]
        int e4 = e - 43200;
        int q = e4 / 24, rem = e4 % 24, mt = rem >> 2, r = rem & 3;
        int c = mt * 16 + q * 4 + r;
        float s = g1[c] * rsqrtf(v1[c] + 1e-5f);
        bn1sw[e4] = b1[c] - m1[c] * s;
    } else if (e < 43392) {                // wout swizzled [q][mt][r]
        int e5 = e - 43296;
        int q = e5 / 24, rem = e5 % 24, mt = rem >> 2, r = rem & 3;
        woutsw[e5] = Wout[mt * 16 + q * 4 + r];
    }
}

// ---------------------------------------------------------------------------
// Main kernel, R20 = R13 structure VERBATIM (the proven 72.5us optimum;
// R14-R19 restructures all regressed: mt-split +12us, 8-wave/half-tile
// correctness fails or +63us, cooperative 6x, fused-csum +16us from
// same-address atomic serialization in L2). Two additive micro-opts only:
//   (a) W0 frags preloaded at entry and PINNED with asm keep-alive (rule:
//       compiler sank plain preloads in R14). 12 x bf16x8 = 48 VGPR; pin
//       placed after X-gen stores so the forced vmcnt wait coincides with
//       the barrier. Layer 1 then has zero global loads.
//   (b) s_setprio(1) around both MFMA phases (T5: independent blocks at
//       3/CU = attn-like wave diversity, m191 +4-7%; NOT lockstep-GEMM).
// Math is bitwise identical to R13 (absmax 3.9e-3).
// ---------------------------------------------------------------------------
__global__ __launch_bounds__(256, 3) void edgenet_main(
    const float* __restrict__ feat, const char* __restrict__ ws,
    const float* __restrict__ boutp, float* __restrict__ sim_out)
{
    __shared__ __align__(16) char smem[51200];   // X then H0 (overlay)
    const int tid = threadIdx.x;
    const int lane = tid & 63;
    const int wave = tid >> 6;
    const int l16 = lane & 15;
    const int quad = lane >> 4;

    // decode triangular tile id -> (bi, bj): cum(bi) = bi*(129-bi)  [R2-verified]
    const int id = blockIdx.x;
    int bi = (int)((129.0f - sqrtf(16641.0f - 4.0f * (float)id)) * 0.5f);
    while (bi > 0 && bi * (129 - bi) > id) --bi;
    while ((bi + 1) * (128 - bi) <= id) ++bi;
    const int bj = 2 * bi + (id - bi * (129 - bi));
    const int i0 = bi << 4;
    const int j0 = bj << 3;
    const int jb = j0 + wave * 2;

    const bf16x8* w0v = (const bf16x8*)(ws + WS_W0BF);
    const bf16x8* w1v = (const bf16x8*)(ws + WS_W1BF);
    const float* bn0sw = (const float*)(ws + WS_BN0SW);
    const float* bn1sw = (const float*)(ws + WS_BN1SW);

    // ---- W0 preload: issue 12 b128 loads now; pinned below (asm) ----
    bf16x8 w0r[3][4];
    #pragma unroll
    for (int mt = 0; mt < 3; ++mt)
        #pragma unroll
        for (int ks = 0; ks < 4; ++ks)
            w0r[mt][ks] = w0v[((wave * 3 + mt) * 4 + ks) * 64 + lane];

    // ---- X gen: fi once, stream 8 fj rows [R8-verified] ----
    {
        int ii = tid & 15, fblk = tid >> 4;
        const float* fi = feat + (i0 + ii) * INF + fblk * 8;
        float4 a0 = *(const float4*)fi;
        float4 a1 = *(const float4*)(fi + 4);
        const float* fj = feat + j0 * INF + fblk * 8;
        char* sp = smem + ii * 272 + fblk * 16;
        #pragma unroll
        for (int jj = 0; jj < 8; ++jj) {
            float4 q0 = *(const float4*)fj;
            float4 q1 = *(const float4*)(fj + 4);
            bf16x8 x;
            x[0] = (__bf16)fabsf(a0.x - q0.x);
            x[1] = (__bf16)fabsf(a0.y - q0.y);
            x[2] = (__bf16)fabsf(a0.z - q0.z);
            x[3] = (__bf16)fabsf(a0.w - q0.w);
            x[4] = (__bf16)fabsf(a1.x - q1.x);
            x[5] = (__bf16)fabsf(a1.y - q1.y);
            x[6] = (__bf16)fabsf(a1.z - q1.z);
            x[7] = (__bf16)fabsf(a1.w - q1.w);
            *(bf16x8*)sp = x;
            fj += INF;
            sp += 16 * 272;
        }
    }

    // keep-alive pin: forces the w0r loads to be retired here (overlapping
    // X-gen) and keeps the 48 VGPRs live through layer 1 (no re-loads).
    #pragma unroll
    for (int mt = 0; mt < 3; ++mt)
        #pragma unroll
        for (int ks = 0; ks < 4; ++ks)
            asm volatile("" : "+v"(w0r[mt][ks]));

    __syncthreads();

    // ---- Layer 1: two nt-halves; acc 48 AGPR; results packed to bf16 regs --
    bf16x4 pk[2][3][4];
    #pragma unroll
    for (int h = 0; h < 2; ++h) {
        v4f acch[3][4];
        #pragma unroll
        for (int mt = 0; mt < 3; ++mt) {
            v4f bb = *(const v4f*)(bn0sw + (quad * 12 + wave * 3 + mt) * 4);
            #pragma unroll
            for (int nt = 0; nt < 4; ++nt)
                acch[mt][nt] = bb;
        }
        __builtin_amdgcn_s_setprio(1);
        #pragma unroll
        for (int ks = 0; ks < 4; ++ks) {
            #pragma unroll
            for (int nt = 0; nt < 4; ++nt) {
                bf16x8 xk = *(const bf16x8*)(smem +
                    ((h * 4 + nt) * 16 + l16) * 272 + ks * 64 + quad * 16);
                acch[0][nt] = __builtin_amdgcn_mfma_f32_16x16x32_bf16(
                    w0r[0][ks], xk, acch[0][nt], 0, 0, 0);
                acch[1][nt] = __builtin_amdgcn_mfma_f32_16x16x32_bf16(
                    w0r[1][ks], xk, acch[1][nt], 0, 0, 0);
                acch[2][nt] = __builtin_amdgcn_mfma_f32_16x16x32_bf16(
                    w0r[2][ks], xk, acch[2][nt], 0, 0, 0);
            }
        }
        __builtin_amdgcn_s_setprio(0);
        // leaky + pack -> bf16 VGPRs (frees the 48 AGPRs for the next half)
        #pragma unroll
        for (int mt = 0; mt < 3; ++mt)
            #pragma unroll
            for (int nt = 0; nt < 4; ++nt) {
                bf16x4 p;
                #pragma unroll
                for (int r = 0; r < 4; ++r) {
                    float v = acch[mt][nt][r];
                    v = fmaxf(v, 0.01f * v);
                    p[r] = (__bf16)v;
                }
                pk[h][mt][nt] = p;
            }
    }
    __syncthreads();   // all X reads done; H0 may overlay

    // ---- H0 write: 24 ds_write_b64 from the packed regs ----
    #pragma unroll
    for (int h = 0; h < 2; ++h)
        #pragma unroll
        for (int mt = 0; mt < 3; ++mt) {
            int chb = (wave * 3 + mt) * 16 + quad * 4;
            #pragma unroll
            for (int nt = 0; nt < 4; ++nt)
                *(bf16x4*)(smem + ((h * 4 + nt) * 16 + l16) * 400 + chb * 2)
                    = pk[h][mt][nt];
        }
    __syncthreads();   // H0 complete (cross-wave channels)

    // ---- Layer 2: wave owns pair ntiles {2w, 2w+1}; H0 rows are B-frags ----
    v4f acc2[6][2];
    #pragma unroll
    for (int mt = 0; mt < 6; ++mt) {
        v4f bb = *(const v4f*)(bn1sw + (quad * 6 + mt) * 4);
        acc2[mt][0] = bb;
        acc2[mt][1] = bb;
    }
    __builtin_amdgcn_s_setprio(1);
    #pragma unroll
    for (int ks = 0; ks < 6; ++ks) {
        bf16x8 h0 = *(const bf16x8*)(smem + ((2 * wave + 0) * 16 + l16) * 400 + ks * 64 + quad * 16);
        bf16x8 h1 = *(const bf16x8*)(smem + ((2 * wave + 1) * 16 + l16) * 400 + ks * 64 + quad * 16);
        #pragma unroll
        for (int mt = 0; mt < 6; ++mt) {
            bf16x8 w = w1v[(mt * 6 + ks) * 64 + lane];
            acc2[mt][0] = __builtin_amdgcn_mfma_f32_16x16x32_bf16(w, h0, acc2[mt][0], 0, 0, 0);
            acc2[mt][1] = __builtin_amdgcn_mfma_f32_16x16x32_bf16(w, h1, acc2[mt][1], 0, 0, 0);
        }
    }
    __builtin_amdgcn_s_setprio(0);

    // ---- epilogue: leaky + dot(wout) + cross-quad butterfly + sigmoid ----
    const float* woutsw = (const float*)(ws + WS_WOUTSW);
    float part[2] = {0.f, 0.f};
    #pragma unroll
    for (int mt = 0; mt < 6; ++mt) {
        v4f wo = *(const v4f*)(woutsw + (quad * 6 + mt) * 4);
        #pragma unroll
        for (int t = 0; t < 2; ++t)
            #pragma unroll
            for (int r = 0; r < 4; ++r) {
                float v = acc2[mt][t][r];
                v = fmaxf(v, 0.01f * v);
                part[t] = fmaf(v, wo[r], part[t]);
            }
    }
    #pragma unroll
    for (int t = 0; t < 2; ++t) {
        part[t] += __shfl_xor(part[t], 16, 64);
        part[t] += __shfl_xor(part[t], 32, 64);
    }
    float z = (quad & 1) ? part[1] : part[0];
    float sv = 1.f / (1.f + expf(-(z + boutp[0])));
    if (quad < 2)
        sim_out[(i0 + l16) * NN + jb + (quad & 1)] = sv;        // direct
    else
        sim_out[(jb + (quad & 1)) * NN + i0 + l16] = sv;        // mirror, 64B runs
}

// ---------------------------------------------------------------------------
// cinv via EXACT symmetry: colsum[j] == rowsum(sim[j][*]). [R9-verified]
// ---------------------------------------------------------------------------
__global__ __launch_bounds__(256) void cinv_kernel(
    const float* __restrict__ sim, float* __restrict__ cinv)
{
    const int lane = threadIdx.x & 63;
    const int wave = threadIdx.x >> 6;
    const float cadd = 1.0f + (float)NN * 1e-6f;
    #pragma unroll
    for (int rr = 0; rr < 4; ++rr) {
        int j = blockIdx.x * 16 + wave * 4 + rr;
        const float4* row = (const float4*)(sim + j * NN);
        float4 a0 = row[lane];
        float4 a1 = row[lane + 64];
        float4 a2 = row[lane + 128];
        float4 a3 = row[lane + 192];
        float s = (a0.x + a0.y + a0.z + a0.w) + (a1.x + a1.y + a1.z + a1.w)
                + (a2.x + a2.y + a2.z + a2.w) + (a3.x + a3.y + a3.z + a3.w);
        #pragma unroll
        for (int off = 1; off < 64; off <<= 1)
            s += __shfl_xor(s, off, 64);
        if (lane == 0)
            cinv[j] = 1.0f / (s + cadd);
    }
}

// ---------------------------------------------------------------------------
// edge[i][j] = (sim + eye + 1e-6) * cinv[j].
// ---------------------------------------------------------------------------
__global__ __launch_bounds__(256) void edge_kernel(
    const float* __restrict__ cinv, const float* __restrict__ sim,
    float* __restrict__ edge)
{
    int i = blockIdx.x;
    int jc = threadIdx.x << 2;
    float4 w = *(const float4*)(cinv + jc);
    float4 s = *(const float4*)(sim + i * NN + jc);
    float4 o;
    o.x = (s.x + (i == jc + 0 ? 1.f : 0.f) + 1e-6f) * w.x;
    o.y = (s.y + (i == jc + 1 ? 1.f : 0.f) + 1e-6f) * w.y;
    o.z = (s.z + (i == jc + 2 ? 1.f : 0.f) + 1e-6f) * w.z;
    o.w = (s.w + (i == jc + 3 ? 1.f : 0.f) + 1e-6f) * w.w;
    *(float4*)(edge + i * NN + jc) = o;
}

extern "C" void kernel_launch(void* const* d_in, const int* in_sizes, int n_in,
                              void* d_out, int out_size, void* d_ws, size_t ws_size,
                              hipStream_t stream)
{
    const float* feat = (const float*)d_in[0];
    const float* W0   = (const float*)d_in[1];
    const float* g0   = (const float*)d_in[2];
    const float* b0   = (const float*)d_in[3];
    const float* m0   = (const float*)d_in[4];
    const float* v0   = (const float*)d_in[5];
    const float* W1   = (const float*)d_in[6];
    const float* g1   = (const float*)d_in[7];
    const float* b1   = (const float*)d_in[8];
    const float* m1   = (const float*)d_in[9];
    const float* v1   = (const float*)d_in[10];
    const float* Wout = (const float*)d_in[11];
    const float* bout = (const float*)d_in[12];
    char* ws = (char*)d_ws;
    float* edge = (float*)d_out;
    float* sim  = edge + NN * NN;
    float* cinv = (float*)(ws + WS_CINV);

    prep_kernel<<<dim3(170), dim3(256), 0, stream>>>(
        W0, g0, b0, m0, v0, W1, g1, b1, m1, v1, Wout, ws);
    edgenet_main<<<dim3(4160), dim3(256), 0, stream>>>(feat, ws, bout, sim);
    cinv_kernel<<<dim3(64), dim3(256), 0, stream>>>(sim, cinv);
    edge_kernel<<<dim3(1024), dim3(256), 0, stream>>>(cinv, sim, edge);
}